// Round 16
// baseline (113.004 us; speedup 1.0000x reference)
//
#include <hip/hip_runtime.h>

// Fused: offset = conv3x3(x,w1)+b1 ; out = deform_conv(x, offset, w2)+b2
// x: (8,3,384,384) f32 NCHW ; out: (8,3,382,382) f32
// R16 = R14 geometry (32x8 tile, 256 threads -- best total 109.96us) +
// R15's verified unified path (no border branch; 'bad' mask flags
// out-of-tile OR out-of-image corners; pass-B exact fixup, execz-skipped).
// R15 lesson: 64x8/512-thread blocks dropped occupancy to 32% -> regression;
// geometry was the problem, not the unification.
// Session evidence (R8-R15): eight structures all land 46.5-50.5us kernel --
// latency-bound equilibrium (no pipe >57%); ILP (R9/R12) and TLP (R3/R15)
// levers exhausted. Hard rules: taps fully unrolled BRANCHLESS (R10/R12:
// branch-in-unroll => VGPR 256 + 500MB spill), no source pipelining of the
// tap loop, no VGPR caps below natural pressure (R3).
// Kept verified: NHWC4 LDS halo staged from NCHW (no transpose kernel),
// XCD batch swizzle (FETCH 39->7MB), pk_fma pairs, NT stores.

#define BB 8
#define HH 384
#define WW 384
#define HO 382
#define WO 382
#define HW (HH * WW)
#define TW 32
#define TH 8
#define TILES_X 12               // ceil(382/32)
#define TILES_Y 48               // ceil(382/8)
#define SROWS 15                 // rows r0-2 .. r0+12
#define SCOLS 39                 // cols w0-2 .. w0+36
#define SSTRIDE 39
#define NTHREADS 256

typedef float v2f __attribute__((ext_vector_type(2), aligned(4)));
typedef float v4f __attribute__((ext_vector_type(4), aligned(16)));

static __device__ __forceinline__ v2f fma2(v2f a, v2f b, v2f c) {
    return __builtin_elementwise_fma(a, b, c);
}
static __device__ __forceinline__ v4f fma4(v4f a, v4f b, v4f c) {
    return __builtin_elementwise_fma(a, b, c);
}

__global__ __launch_bounds__(NTHREADS) void deform_tiled(
    const float* __restrict__ x,
    const float* __restrict__ w1,
    const float* __restrict__ b1,
    const float* __restrict__ w2,
    const float* __restrict__ b2,
    float* __restrict__ out)
{
    __shared__ v4f  s_tile[SROWS * SSTRIDE];   // 585*16 = 9.4KB
    __shared__ float s_w1p[486];   // pairs: [((j*3+c)*9+k)*2+comp]
    __shared__ float s_b1[18];
    __shared__ float s_w2p[54];    // pairs (o=0,1): [(k*3+c)*2+o]
    __shared__ float s_w2s[27];    // scalar o=2:    [k*3+c]
    __shared__ float s_b2[3];

    for (int i = threadIdx.x; i < 486; i += NTHREADS) {
        const int oc = i / 27, rem = i % 27, c = rem / 9, j = rem % 9;
        const int k = oc >> 1, comp = oc & 1;
        s_w1p[((j * 3 + c) * 9 + k) * 2 + comp] = w1[i];
    }
    if (threadIdx.x < 81) {
        const int i = threadIdx.x;
        const int o = i / 27, c = (i % 27) / 9, k = i % 9;
        if (o < 2) s_w2p[(k * 3 + c) * 2 + o] = w2[i];
        else       s_w2s[k * 3 + c] = w2[i];
    }
    if (threadIdx.x < 18) s_b1[threadIdx.x] = b1[threadIdx.x];
    if (threadIdx.x < 3)  s_b2[threadIdx.x] = b2[threadIdx.x];

    const int b  = blockIdx.x & 7;            // XCD-locality: batch per XCD
    const int t  = blockIdx.x >> 3;
    const int tx = t % TILES_X;
    const int ty = t / TILES_X;
    const int w0 = tx * TW;
    const int r0 = ty * TH;

    const float* xp0 = x + (long)b * 3 * HW;
    const float* xp1 = xp0 + HW;
    const float* xp2 = xp0 + 2 * HW;

    // ---- stage halo tile, transposing NCHW -> NHWC4 on the fly ----
    const int gr0 = r0 - 2, gc0 = w0 - 2;
    for (int s = threadIdx.x; s < SROWS * SCOLS; s += NTHREADS) {
        const int sr = s / SCOLS, sc = s - sr * SCOLS;
        const int gy = min(max(gr0 + sr, 0), HH - 1);
        const int gx = min(max(gc0 + sc, 0), WW - 1);
        const int base = gy * WW + gx;
        v4f v;
        v.x = xp0[base];
        v.y = xp1[base];
        v.z = xp2[base];
        v.w = 0.f;
        s_tile[sr * SSTRIDE + sc] = v;
    }
    __syncthreads();

    const int wo_in = threadIdx.x & 31;
    const int ho_in = threadIdx.x >> 5;
    const int wo = w0 + wo_in;
    const int ho = r0 + ho_in;
    if (wo >= WO || ho >= HO) return;         // after the only barrier

    // ---- Phase 1: 9 (dy,dx) pairs from LDS tile, packed FMA ----
    v2f off2[9];
#pragma unroll
    for (int k = 0; k < 9; ++k) {
        v2f v; v.x = s_b1[2 * k]; v.y = s_b1[2 * k + 1];
        off2[k] = v;
    }

    const v2f* w1p = (const v2f*)s_w1p;
#pragma unroll
    for (int j = 0; j < 9; ++j) {
        const int i = j / 3, jj = j % 3;
        const v4f q = s_tile[(ho_in + 2 + i) * SSTRIDE + (wo_in + 2 + jj)];
#pragma unroll
        for (int c = 0; c < 3; ++c) {
            const float xc = (c == 0) ? q.x : (c == 1) ? q.y : q.z;
            v2f xcv; xcv.x = xc; xcv.y = xc;
            const v2f* wrow = w1p + (j * 3 + c) * 9;
#pragma unroll
            for (int k = 0; k < 9; ++k)
                off2[k] = fma2(xcv, wrow[k], off2[k]);
        }
    }

    // ---- Phase 2, Pass A: 9 taps fully unrolled, branchless ----
    float acc0 = s_b2[0], acc1 = s_b2[1], acc2 = s_b2[2];
    const v2f* w2p = (const v2f*)s_w2p;

    unsigned bad = 0u;
#pragma unroll
    for (int k = 0; k < 9; ++k) {
        const int kh = k / 3, kw = k - kh * 3;
        v2f pos; pos.x = (float)(ho + kh); pos.y = (float)(wo + kw);
        pos += off2[k];
        const v2f fl = __builtin_elementwise_floor(pos);
        const v2f fr = pos - fl;
        const int y0 = (int)fl.x;
        const int x0 = (int)fl.y;
        const int ly0 = y0 - gr0;
        const int lx  = x0 - gc0;

        // flag if any corner leaves the IMAGE or the TILE
        const bool ok = ((unsigned)y0 <= (unsigned)(HH - 2)) &
                        ((unsigned)x0 <= (unsigned)(WW - 2)) &
                        ((unsigned)ly0 <= (unsigned)(SROWS - 2)) &
                        ((unsigned)lx  <= (unsigned)(SCOLS - 2));
        bad |= ok ? 0u : (1u << k);

        const float g00 = (1.f - fr.x) * (1.f - fr.y);
        const float g01 = (1.f - fr.x) * fr.y;
        const float g10 = fr.x * (1.f - fr.y);
        const float g11 = fr.x * fr.y;

        const int cy0 = min(max(ly0, 0), SROWS - 2);
        const int cx  = min(max(lx, 0),  SCOLS - 2);
        const v4f* p0 = s_tile + cy0 * SSTRIDE + cx;
        const v4f* p1 = p0 + SSTRIDE;
        const v4f q00 = p0[0], q01 = p0[1];
        const v4f q10 = p1[0], q11 = p1[1];

        v4f gv; gv.x = g00; gv.y = g00; gv.z = g00; gv.w = g00;
        v4f t4 = gv * q00;
        gv.x = g01; gv.y = g01; gv.z = g01; gv.w = g01;
        t4 = fma4(gv, q01, t4);
        gv.x = g10; gv.y = g10; gv.z = g10; gv.w = g10;
        t4 = fma4(gv, q10, t4);
        gv.x = g11; gv.y = g11; gv.z = g11; gv.w = g11;
        t4 = fma4(gv, q11, t4);

        const float v0 = t4.x, v1 = t4.y, v2v = t4.z;

        v2f acc01; acc01.x = acc0; acc01.y = acc1;
        v2f vv;
        vv.x = v0;  vv.y = v0;  acc01 = fma2(vv, w2p[k * 3 + 0], acc01);
        vv.x = v1;  vv.y = v1;  acc01 = fma2(vv, w2p[k * 3 + 1], acc01);
        vv.x = v2v; vv.y = v2v; acc01 = fma2(vv, w2p[k * 3 + 2], acc01);
        acc0 = acc01.x; acc1 = acc01.y;
        acc2 = fmaf(s_w2s[k * 3 + 0], v0, acc2);
        acc2 = fmaf(s_w2s[k * 3 + 1], v1, acc2);
        acc2 = fmaf(s_w2s[k * 3 + 2], v2v, acc2);
    }

    // ---- Pass B: exact fixup for flagged taps (execz-skipped mostly) ----
    if (bad) {
#pragma unroll 1
        for (int k = 0; k < 9; ++k) {
            if ((bad >> k) & 1u) {
                const int kh = k / 3, kw = k - kh * 3;
                v2f pos; pos.x = (float)(ho + kh); pos.y = (float)(wo + kw);
                pos += off2[k];
                const v2f fl = __builtin_elementwise_floor(pos);
                const v2f fr = pos - fl;
                const int y0 = (int)fl.x;
                const int x0 = (int)fl.y;

                // -- wrong contribution (identical ops to pass A) --
                const int ly0 = y0 - gr0;
                const int lx  = x0 - gc0;
                const float a00 = (1.f - fr.x) * (1.f - fr.y);
                const float a01 = (1.f - fr.x) * fr.y;
                const float a10 = fr.x * (1.f - fr.y);
                const float a11 = fr.x * fr.y;
                const int cy0 = min(max(ly0, 0), SROWS - 2);
                const int cx  = min(max(lx, 0),  SCOLS - 2);
                const v4f* p0 = s_tile + cy0 * SSTRIDE + cx;
                const v4f* p1 = p0 + SSTRIDE;
                const v4f w00v = p0[0], w01v = p0[1];
                const v4f w10v = p1[0], w11v = p1[1];
                v4f gv; gv.x = a00; gv.y = a00; gv.z = a00; gv.w = a00;
                v4f tw = gv * w00v;
                gv.x = a01; gv.y = a01; gv.z = a01; gv.w = a01;
                tw = fma4(gv, w01v, tw);
                gv.x = a10; gv.y = a10; gv.z = a10; gv.w = a10;
                tw = fma4(gv, w10v, tw);
                gv.x = a11; gv.y = a11; gv.z = a11; gv.w = a11;
                tw = fma4(gv, w11v, tw);

                // -- right contribution (exact reference semantics) --
                const int ry0 = min(max(y0, 0), HH - 1);
                const int ry1 = min(max(y0 + 1, 0), HH - 1);
                const int xbs = min(max(x0, 0), WW - 2);
                const bool vy0 = (y0 >= 0) & (y0 <= HH - 1);
                const bool vy1 = (y0 >= -1) & (y0 <= HH - 2);
                const bool vx0 = (x0 >= 0) & (x0 <= WW - 1);
                const bool vx1 = (x0 >= -1) & (x0 <= WW - 2);
                const float wy0m = vy0 ? (1.f - fr.x) : 0.f;
                const float wy1m = vy1 ? fr.x : 0.f;
                const float wx0m = vx0 ? (1.f - fr.y) : 0.f;
                const float wx1m = vx1 ? fr.y : 0.f;
                const bool selA = (x0 >= WW - 1);
                const bool selB = (x0 >= 0);
                const float e0 = (selA ? 0.f : wx0m) + (selB ? 0.f : wx1m);
                const float e1 = (selA ? wx0m : 0.f) + (selB ? wx1m : 0.f);
                const float g00 = wy0m * e0, g01 = wy0m * e1;
                const float g10 = wy1m * e0, g11 = wy1m * e1;
                const int o0 = ry0 * WW + xbs;
                const int o1 = ry1 * WW + xbs;
                v4f q00, q01, q10, q11;
                q00.x = xp0[o0];     q00.y = xp1[o0];     q00.z = xp2[o0];     q00.w = 0.f;
                q01.x = xp0[o0 + 1]; q01.y = xp1[o0 + 1]; q01.z = xp2[o0 + 1]; q01.w = 0.f;
                q10.x = xp0[o1];     q10.y = xp1[o1];     q10.z = xp2[o1];     q10.w = 0.f;
                q11.x = xp0[o1 + 1]; q11.y = xp1[o1 + 1]; q11.z = xp2[o1 + 1]; q11.w = 0.f;
                gv.x = g00; gv.y = g00; gv.z = g00; gv.w = g00;
                v4f tr = gv * q00;
                gv.x = g01; gv.y = g01; gv.z = g01; gv.w = g01;
                tr = fma4(gv, q01, tr);
                gv.x = g10; gv.y = g10; gv.z = g10; gv.w = g10;
                tr = fma4(gv, q10, tr);
                gv.x = g11; gv.y = g11; gv.z = g11; gv.w = g11;
                tr = fma4(gv, q11, tr);

                const float d0 = tr.x - tw.x;
                const float d1 = tr.y - tw.y;
                const float d2 = tr.z - tw.z;

                v2f acc01; acc01.x = acc0; acc01.y = acc1;
                v2f vv;
                vv.x = d0; vv.y = d0; acc01 = fma2(vv, w2p[k * 3 + 0], acc01);
                vv.x = d1; vv.y = d1; acc01 = fma2(vv, w2p[k * 3 + 1], acc01);
                vv.x = d2; vv.y = d2; acc01 = fma2(vv, w2p[k * 3 + 2], acc01);
                acc0 = acc01.x; acc1 = acc01.y;
                acc2 = fmaf(s_w2s[k * 3 + 0], d0, acc2);
                acc2 = fmaf(s_w2s[k * 3 + 1], d1, acc2);
                acc2 = fmaf(s_w2s[k * 3 + 2], d2, acc2);
            }
        }
    }

    const long obase = ((long)(b * 3) * HO + ho) * WO + wo;
    __builtin_nontemporal_store(acc0, out + obase);
    __builtin_nontemporal_store(acc1, out + obase + (long)HO * WO);
    __builtin_nontemporal_store(acc2, out + obase + 2L * HO * WO);
}

extern "C" void kernel_launch(void* const* d_in, const int* in_sizes, int n_in,
                              void* d_out, int out_size, void* d_ws, size_t ws_size,
                              hipStream_t stream) {
    const float* x  = (const float*)d_in[0];
    const float* w1 = (const float*)d_in[1];
    const float* b1 = (const float*)d_in[2];
    const float* w2 = (const float*)d_in[3];
    const float* b2 = (const float*)d_in[4];
    float* out = (float*)d_out;

    const int blocks = TILES_X * TILES_Y * BB;   // 12*48*8 = 4608
    deform_tiled<<<blocks, NTHREADS, 0, stream>>>(x, w1, b1, w2, b2, out);
}

// Round 17
// 109.329 us; speedup vs baseline: 1.0336x; 1.0336x over previous
//
#include <hip/hip_runtime.h>

// FINAL (= R14, best measured: total 109.96us, kernel 48.6us, VGPR 40).
// Fused: offset = conv3x3(x,w1)+b1 ; out = deform_conv(x, offset, w2)+b2
// x: (8,3,384,384) f32 NCHW ; out: (8,3,382,382) f32
//
// Session summary (16 rounds): 152.8 -> 109.96us total (kernel 92 -> 48.6).
// Verified wins: XCD batch swizzle (b=blockIdx&7, FETCH 39->7MB); NHWC4
// layout so each bilinear corner = one 16B load (69->46.5us); LDS halo tile
// staged directly from NCHW (kills the 13us transpose kernel); pk_fma
// packing; NT stores; interior-block fast path w/ exact-fixup mask.
// Verified dead ends: VGPR caps below natural pressure (R3: spill cliff);
// >1 px/thread (R2: occupancy); source-level software pipelining of the tap
// loop (R9 re-serialized, R12 VGPR 256 + 500MB spill); branch inside an
// unrolled tap loop (R10: live-range explosion); 512-thread blocks (R15);
// unified-path-everywhere (R16: mask overhead on every block).
// Plateau: nine structures all land 46.5-50.5us kernel with no pipe >57%
// busy -- a dependent-chain latency equilibrium (offset->floor->addr->load->
// FMA x wave parallelism), not a roofline. Breaking it needs asm-level
// waitcnt scheduling the HIP compiler defeats at source level.

#define BB 8
#define HH 384
#define WW 384
#define HO 382
#define WO 382
#define HW (HH * WW)
#define TW 32
#define TH 8
#define TILES_X 12               // ceil(382/32)
#define TILES_Y 48               // ceil(382/8)
#define SROWS 15                 // rows r0-2 .. r0+12
#define SCOLS 39                 // cols w0-2 .. w0+36
#define SSTRIDE 39

typedef float v2f __attribute__((ext_vector_type(2), aligned(4)));
typedef float v4f __attribute__((ext_vector_type(4), aligned(16)));

static __device__ __forceinline__ v2f fma2(v2f a, v2f b, v2f c) {
    return __builtin_elementwise_fma(a, b, c);
}
static __device__ __forceinline__ v4f fma4(v4f a, v4f b, v4f c) {
    return __builtin_elementwise_fma(a, b, c);
}

__global__ __launch_bounds__(256) void deform_tiled(
    const float* __restrict__ x,
    const float* __restrict__ w1,
    const float* __restrict__ b1,
    const float* __restrict__ w2,
    const float* __restrict__ b2,
    float* __restrict__ out)
{
    __shared__ v4f  s_tile[SROWS * SSTRIDE];   // 585*16 = 9.4KB
    __shared__ float s_w1p[486];   // pairs: [((j*3+c)*9+k)*2+comp]
    __shared__ float s_b1[18];
    __shared__ float s_w2p[54];    // pairs (o=0,1): [(k*3+c)*2+o]
    __shared__ float s_w2s[27];    // scalar o=2:    [k*3+c]
    __shared__ float s_b2[3];

    for (int i = threadIdx.x; i < 486; i += 256) {
        const int oc = i / 27, rem = i % 27, c = rem / 9, j = rem % 9;
        const int k = oc >> 1, comp = oc & 1;
        s_w1p[((j * 3 + c) * 9 + k) * 2 + comp] = w1[i];
    }
    if (threadIdx.x < 81) {
        const int i = threadIdx.x;
        const int o = i / 27, c = (i % 27) / 9, k = i % 9;
        if (o < 2) s_w2p[(k * 3 + c) * 2 + o] = w2[i];
        else       s_w2s[k * 3 + c] = w2[i];
    }
    if (threadIdx.x < 18) s_b1[threadIdx.x] = b1[threadIdx.x];
    if (threadIdx.x < 3)  s_b2[threadIdx.x] = b2[threadIdx.x];

    const int b  = blockIdx.x & 7;            // XCD-locality: batch per XCD
    const int t  = blockIdx.x >> 3;
    const int tx = t % TILES_X;
    const int ty = t / TILES_X;
    const int w0 = tx * TW;
    const int r0 = ty * TH;

    const float* xp0 = x + (long)b * 3 * HW;
    const float* xp1 = xp0 + HW;
    const float* xp2 = xp0 + 2 * HW;

    // ---- stage halo tile, transposing NCHW -> NHWC4 on the fly ----
    const int gr0 = r0 - 2, gc0 = w0 - 2;
    for (int s = threadIdx.x; s < SROWS * SCOLS; s += 256) {
        const int sr = s / SCOLS, sc = s - sr * SCOLS;
        const int gy = min(max(gr0 + sr, 0), HH - 1);
        const int gx = min(max(gc0 + sc, 0), WW - 1);
        const int base = gy * WW + gx;
        v4f v;
        v.x = xp0[base];
        v.y = xp1[base];
        v.z = xp2[base];
        v.w = 0.f;
        s_tile[sr * SSTRIDE + sc] = v;
    }
    __syncthreads();

    const int wo_in = threadIdx.x & 31;
    const int ho_in = threadIdx.x >> 5;
    const int wo = w0 + wo_in;
    const int ho = r0 + ho_in;
    if (wo >= WO || ho >= HO) return;         // after the only barrier

    // ---- Phase 1: 9 (dy,dx) pairs from LDS tile, packed FMA ----
    v2f off2[9];
#pragma unroll
    for (int k = 0; k < 9; ++k) {
        v2f v; v.x = s_b1[2 * k]; v.y = s_b1[2 * k + 1];
        off2[k] = v;
    }

    const v2f* w1p = (const v2f*)s_w1p;
#pragma unroll
    for (int j = 0; j < 9; ++j) {
        const int i = j / 3, jj = j % 3;
        const v4f q = s_tile[(ho_in + 2 + i) * SSTRIDE + (wo_in + 2 + jj)];
#pragma unroll
        for (int c = 0; c < 3; ++c) {
            const float xc = (c == 0) ? q.x : (c == 1) ? q.y : q.z;
            v2f xcv; xcv.x = xc; xcv.y = xc;
            const v2f* wrow = w1p + (j * 3 + c) * 9;
#pragma unroll
            for (int k = 0; k < 9; ++k)
                off2[k] = fma2(xcv, wrow[k], off2[k]);
        }
    }

    // ---- Phase 2 ----
    float acc0 = s_b2[0], acc1 = s_b2[1], acc2 = s_b2[2];
    const v2f* w2p = (const v2f*)s_w2p;

    const bool interior = (gr0 >= 0) & (gc0 >= 0) &
                          (gr0 + SROWS <= HH) & (gc0 + SCOLS <= WW);

    if (interior) {
        // ======== Pass A: fully unrolled, branchless, mask collection ======
        unsigned bad = 0u;
#pragma unroll
        for (int k = 0; k < 9; ++k) {
            const int kh = k / 3, kw = k - kh * 3;
            v2f pos; pos.x = (float)(ho + kh); pos.y = (float)(wo + kw);
            pos += off2[k];
            const v2f fl = __builtin_elementwise_floor(pos);
            const v2f fr = pos - fl;
            const int y0 = (int)fl.x;
            const int x0 = (int)fl.y;
            const int ly0 = y0 - gr0;
            const int lx  = x0 - gc0;

            bad |= (((unsigned)ly0 > (unsigned)(SROWS - 2)) |
                    ((unsigned)lx  > (unsigned)(SCOLS - 2))) ? (1u << k) : 0u;

            const float g00 = (1.f - fr.x) * (1.f - fr.y);
            const float g01 = (1.f - fr.x) * fr.y;
            const float g10 = fr.x * (1.f - fr.y);
            const float g11 = fr.x * fr.y;

            const int cy0 = min(max(ly0, 0), SROWS - 2);
            const int cx  = min(max(lx, 0),  SCOLS - 2);
            const v4f* p0 = s_tile + cy0 * SSTRIDE + cx;
            const v4f* p1 = p0 + SSTRIDE;
            const v4f q00 = p0[0], q01 = p0[1];
            const v4f q10 = p1[0], q11 = p1[1];

            v4f gv; gv.x = g00; gv.y = g00; gv.z = g00; gv.w = g00;
            v4f t4 = gv * q00;
            gv.x = g01; gv.y = g01; gv.z = g01; gv.w = g01;
            t4 = fma4(gv, q01, t4);
            gv.x = g10; gv.y = g10; gv.z = g10; gv.w = g10;
            t4 = fma4(gv, q10, t4);
            gv.x = g11; gv.y = g11; gv.z = g11; gv.w = g11;
            t4 = fma4(gv, q11, t4);

            const float v0 = t4.x, v1 = t4.y, v2v = t4.z;

            v2f acc01; acc01.x = acc0; acc01.y = acc1;
            v2f vv;
            vv.x = v0;  vv.y = v0;  acc01 = fma2(vv, w2p[k * 3 + 0], acc01);
            vv.x = v1;  vv.y = v1;  acc01 = fma2(vv, w2p[k * 3 + 1], acc01);
            vv.x = v2v; vv.y = v2v; acc01 = fma2(vv, w2p[k * 3 + 2], acc01);
            acc0 = acc01.x; acc1 = acc01.y;
            acc2 = fmaf(s_w2s[k * 3 + 0], v0, acc2);
            acc2 = fmaf(s_w2s[k * 3 + 1], v1, acc2);
            acc2 = fmaf(s_w2s[k * 3 + 2], v2v, acc2);
        }

        // ======== Pass B: exact fixup for >8-sigma taps (execz-skipped) ====
        if (bad) {
#pragma unroll 1
            for (int k = 0; k < 9; ++k) {
                if ((bad >> k) & 1u) {
                    const int kh = k / 3, kw = k - kh * 3;
                    v2f pos; pos.x = (float)(ho + kh); pos.y = (float)(wo + kw);
                    pos += off2[k];
                    const v2f fl = __builtin_elementwise_floor(pos);
                    const v2f fr = pos - fl;
                    const int y0 = (int)fl.x;
                    const int x0 = (int)fl.y;

                    // -- wrong contribution (identical ops to pass A) --
                    const int ly0 = y0 - gr0;
                    const int lx  = x0 - gc0;
                    const float a00 = (1.f - fr.x) * (1.f - fr.y);
                    const float a01 = (1.f - fr.x) * fr.y;
                    const float a10 = fr.x * (1.f - fr.y);
                    const float a11 = fr.x * fr.y;
                    const int cy0 = min(max(ly0, 0), SROWS - 2);
                    const int cx  = min(max(lx, 0),  SCOLS - 2);
                    const v4f* p0 = s_tile + cy0 * SSTRIDE + cx;
                    const v4f* p1 = p0 + SSTRIDE;
                    const v4f w00v = p0[0], w01v = p0[1];
                    const v4f w10v = p1[0], w11v = p1[1];
                    v4f gv; gv.x = a00; gv.y = a00; gv.z = a00; gv.w = a00;
                    v4f tw = gv * w00v;
                    gv.x = a01; gv.y = a01; gv.z = a01; gv.w = a01;
                    tw = fma4(gv, w01v, tw);
                    gv.x = a10; gv.y = a10; gv.z = a10; gv.w = a10;
                    tw = fma4(gv, w10v, tw);
                    gv.x = a11; gv.y = a11; gv.z = a11; gv.w = a11;
                    tw = fma4(gv, w11v, tw);

                    // -- right contribution (exact reference semantics) --
                    const int ry0 = min(max(y0, 0), HH - 1);
                    const int ry1 = min(max(y0 + 1, 0), HH - 1);
                    const int xbs = min(max(x0, 0), WW - 2);
                    const bool vy0 = (y0 >= 0) & (y0 <= HH - 1);
                    const bool vy1 = (y0 >= -1) & (y0 <= HH - 2);
                    const bool vx0 = (x0 >= 0) & (x0 <= WW - 1);
                    const bool vx1 = (x0 >= -1) & (x0 <= WW - 2);
                    const float wy0m = vy0 ? (1.f - fr.x) : 0.f;
                    const float wy1m = vy1 ? fr.x : 0.f;
                    const float wx0m = vx0 ? (1.f - fr.y) : 0.f;
                    const float wx1m = vx1 ? fr.y : 0.f;
                    const bool selA = (x0 >= WW - 1);
                    const bool selB = (x0 >= 0);
                    const float e0 = (selA ? 0.f : wx0m) + (selB ? 0.f : wx1m);
                    const float e1 = (selA ? wx0m : 0.f) + (selB ? wx1m : 0.f);
                    const float g00 = wy0m * e0, g01 = wy0m * e1;
                    const float g10 = wy1m * e0, g11 = wy1m * e1;
                    const int o0 = ry0 * WW + xbs;
                    const int o1 = ry1 * WW + xbs;
                    v4f q00, q01, q10, q11;
                    q00.x = xp0[o0];     q00.y = xp1[o0];     q00.z = xp2[o0];     q00.w = 0.f;
                    q01.x = xp0[o0 + 1]; q01.y = xp1[o0 + 1]; q01.z = xp2[o0 + 1]; q01.w = 0.f;
                    q10.x = xp0[o1];     q10.y = xp1[o1];     q10.z = xp2[o1];     q10.w = 0.f;
                    q11.x = xp0[o1 + 1]; q11.y = xp1[o1 + 1]; q11.z = xp2[o1 + 1]; q11.w = 0.f;
                    gv.x = g00; gv.y = g00; gv.z = g00; gv.w = g00;
                    v4f tr = gv * q00;
                    gv.x = g01; gv.y = g01; gv.z = g01; gv.w = g01;
                    tr = fma4(gv, q01, tr);
                    gv.x = g10; gv.y = g10; gv.z = g10; gv.w = g10;
                    tr = fma4(gv, q10, tr);
                    gv.x = g11; gv.y = g11; gv.z = g11; gv.w = g11;
                    tr = fma4(gv, q11, tr);

                    const float d0 = tr.x - tw.x;
                    const float d1 = tr.y - tw.y;
                    const float d2 = tr.z - tw.z;

                    v2f acc01; acc01.x = acc0; acc01.y = acc1;
                    v2f vv;
                    vv.x = d0; vv.y = d0; acc01 = fma2(vv, w2p[k * 3 + 0], acc01);
                    vv.x = d1; vv.y = d1; acc01 = fma2(vv, w2p[k * 3 + 1], acc01);
                    vv.x = d2; vv.y = d2; acc01 = fma2(vv, w2p[k * 3 + 2], acc01);
                    acc0 = acc01.x; acc1 = acc01.y;
                    acc2 = fmaf(s_w2s[k * 3 + 0], d0, acc2);
                    acc2 = fmaf(s_w2s[k * 3 + 1], d1, acc2);
                    acc2 = fmaf(s_w2s[k * 3 + 2], d2, acc2);
                }
            }
        }
    } else {
        // ---- border blocks (20%): rolled exact loop ----
#pragma unroll 1
        for (int k = 0; k < 9; ++k) {
            const int kh = k / 3, kw = k - kh * 3;
            v2f pos; pos.x = (float)(ho + kh); pos.y = (float)(wo + kw);
            pos += off2[k];
            const v2f fl = __builtin_elementwise_floor(pos);
            const v2f fr = pos - fl;
            const int y0 = (int)fl.x;
            const int x0 = (int)fl.y;

            const int ry0 = min(max(y0, 0), HH - 1);
            const int ry1 = min(max(y0 + 1, 0), HH - 1);
            const int xbs = min(max(x0, 0), WW - 2);

            const bool vy0 = (y0 >= 0) & (y0 <= HH - 1);
            const bool vy1 = (y0 >= -1) & (y0 <= HH - 2);
            const bool vx0 = (x0 >= 0) & (x0 <= WW - 1);
            const bool vx1 = (x0 >= -1) & (x0 <= WW - 2);
            const float wy0m = vy0 ? (1.f - fr.x) : 0.f;
            const float wy1m = vy1 ? fr.x : 0.f;
            const float wx0m = vx0 ? (1.f - fr.y) : 0.f;
            const float wx1m = vx1 ? fr.y : 0.f;

            const bool selA = (x0 >= WW - 1);
            const bool selB = (x0 >= 0);
            const float e0 = (selA ? 0.f : wx0m) + (selB ? 0.f : wx1m);
            const float e1 = (selA ? wx0m : 0.f) + (selB ? wx1m : 0.f);
            const float g00 = wy0m * e0, g01 = wy0m * e1;
            const float g10 = wy1m * e0, g11 = wy1m * e1;

            const int ly0 = ry0 - gr0;
            const int ly1 = ry1 - gr0;
            const int lx  = xbs - gc0;
            const bool inTile = ((unsigned)ly0 <= SROWS - 1) &
                                ((unsigned)ly1 <= SROWS - 1) &
                                ((unsigned)lx  <= SCOLS - 2);

            const int cy0 = min(max(ly0, 0), SROWS - 1);
            const int cy1 = min(max(ly1, 0), SROWS - 1);
            const int cx  = min(max(lx, 0),  SCOLS - 2);
            const v4f* p0 = s_tile + cy0 * SSTRIDE + cx;
            const v4f* p1 = s_tile + cy1 * SSTRIDE + cx;
            v4f q00 = p0[0], q01 = p0[1];
            v4f q10 = p1[0], q11 = p1[1];

            if (!inTile) {
                const int o0 = ry0 * WW + xbs;
                const int o1 = ry1 * WW + xbs;
                q00.x = xp0[o0];     q00.y = xp1[o0];     q00.z = xp2[o0];
                q01.x = xp0[o0 + 1]; q01.y = xp1[o0 + 1]; q01.z = xp2[o0 + 1];
                q10.x = xp0[o1];     q10.y = xp1[o1];     q10.z = xp2[o1];
                q11.x = xp0[o1 + 1]; q11.y = xp1[o1 + 1]; q11.z = xp2[o1 + 1];
            }

            v4f gv; gv.x = g00; gv.y = g00; gv.z = g00; gv.w = g00;
            v4f t4 = gv * q00;
            gv.x = g01; gv.y = g01; gv.z = g01; gv.w = g01;
            t4 = fma4(gv, q01, t4);
            gv.x = g10; gv.y = g10; gv.z = g10; gv.w = g10;
            t4 = fma4(gv, q10, t4);
            gv.x = g11; gv.y = g11; gv.z = g11; gv.w = g11;
            t4 = fma4(gv, q11, t4);

            const float v0 = t4.x, v1 = t4.y, v2v = t4.z;

            v2f acc01; acc01.x = acc0; acc01.y = acc1;
            v2f vv;
            vv.x = v0;  vv.y = v0;  acc01 = fma2(vv, w2p[k * 3 + 0], acc01);
            vv.x = v1;  vv.y = v1;  acc01 = fma2(vv, w2p[k * 3 + 1], acc01);
            vv.x = v2v; vv.y = v2v; acc01 = fma2(vv, w2p[k * 3 + 2], acc01);
            acc0 = acc01.x; acc1 = acc01.y;
            acc2 = fmaf(s_w2s[k * 3 + 0], v0, acc2);
            acc2 = fmaf(s_w2s[k * 3 + 1], v1, acc2);
            acc2 = fmaf(s_w2s[k * 3 + 2], v2v, acc2);
        }
    }

    const long obase = ((long)(b * 3) * HO + ho) * WO + wo;
    __builtin_nontemporal_store(acc0, out + obase);
    __builtin_nontemporal_store(acc1, out + obase + (long)HO * WO);
    __builtin_nontemporal_store(acc2, out + obase + 2L * HO * WO);
}

extern "C" void kernel_launch(void* const* d_in, const int* in_sizes, int n_in,
                              void* d_out, int out_size, void* d_ws, size_t ws_size,
                              hipStream_t stream) {
    const float* x  = (const float*)d_in[0];
    const float* w1 = (const float*)d_in[1];
    const float* b1 = (const float*)d_in[2];
    const float* w2 = (const float*)d_in[3];
    const float* b2 = (const float*)d_in[4];
    float* out = (float*)d_out;

    const int blocks = TILES_X * TILES_Y * BB;   // 12*48*8 = 4608
    deform_tiled<<<blocks, 256, 0, stream>>>(x, w1, b1, w2, b2, out);
}